// Round 9
// baseline (49.043 us; speedup 1.0000x reference)
//
#include <hip/hip_runtime.h>
#include <math.h>

#define L_OBS   512
#define NSEG    8192
#define NB      8
#define EPS_PAR 1e-4f
#define ANG_STEP 0.012271846644580566f  // 2*pi / 512
#define INV_STEP 81.48733086305042f     // 1/ANG_STEP
#define PI_F     3.14159265358979f
#define TWOPI_F  6.28318530717959f
#define INV_2PI  0.15915494309189535f
#define MARG     2e-3f                  // rad, >> atan2f fp error

#define NBK   32                        // beam buckets per b (16 beams each)
#define CAP   4064                      // u16 entries per (b,bucket)
#define LCAP  288                       // LDS staging per (block,bucket)

// ws layout: u32 cnt[NB][NBK] (1 KB) ; u16 list[NB][NBK][CAP]
#define WS_CNT_BYTES  (NB * NBK * 4)
#define WS_NEED       (WS_CNT_BYTES + (size_t)NB * NBK * CAP * 2)

// Build candidate lists: thread = (b, seg). Wedge = arc between directions to
// the two endpoints (width < pi); any beam whose angle lies outside the wedge
// cannot hit (u_b in [0,1] & u_a>=0 impossible) -> superset culling is exact.
__global__ __launch_bounds__(512) void build_kernel(
    const float4* __restrict__ seg, const float* __restrict__ pose,
    unsigned* __restrict__ cnt, unsigned short* __restrict__ list) {
    __shared__ unsigned short stage[NBK][LCAP];
    __shared__ int      cntL[NBK];
    __shared__ unsigned baseL[NBK];

    const int b  = blockIdx.x >> 4;               // 128 blocks = 8b * 16 chunks
    const int s0 = ((blockIdx.x & 15) << 9) + threadIdx.x;
    const float x1 = pose[b * 3 + 0];
    const float y1 = pose[b * 3 + 1];
    const float th = pose[b * 3 + 2];

    if (threadIdx.x < NBK) cntL[threadIdx.x] = 0;
    __syncthreads();

    float4 v = seg[s0];
    float aA = atan2f(v.y - y1, v.x - x1);
    float aB = atan2f(v.w - y1, v.z - x1);
    float d  = aB - aA;
    if (d > PI_F) d -= TWOPI_F; else if (d < -PI_F) d += TWOPI_F;
    float lo  = (d >= 0.0f) ? aA : aB;
    float wdt = fabsf(d);

    int ilo, ihi;
    if (wdt > PI_F - 0.02f) {          // degenerate/near-pi: all buckets
        ilo = 512; ihi = 1023;
    } else {
        float a = lo - th;
        a -= floorf(a * INV_2PI) * TWOPI_F;            // [0, 2pi)
        ilo = (int)floorf((a - MARG) * INV_STEP) + 512;            // >= 511
        ihi = (int)floorf((a + wdt + MARG) * INV_STEP) + 1 + 512;
    }
    int blo = ilo >> 4, bhi = ihi >> 4;
    int nb = bhi - blo + 1; if (nb > NBK) nb = NBK;

    for (int j = 0; j < nb; ++j) {
        int bk = (blo + j) & (NBK - 1);
        int pos = atomicAdd(&cntL[bk], 1);
        if (pos < LCAP) {
            stage[bk][pos] = (unsigned short)s0;
        } else {                                        // rare spill
            unsigned g = atomicAdd(&cnt[b * NBK + bk], 1u);
            if (g < CAP) list[(size_t)(b * NBK + bk) * CAP + g] = (unsigned short)s0;
        }
    }
    __syncthreads();

    if (threadIdx.x < NBK) {
        int c = cntL[threadIdx.x]; if (c > LCAP) c = LCAP;
        baseL[threadIdx.x] = atomicAdd(&cnt[b * NBK + threadIdx.x], (unsigned)c);
        cntL[threadIdx.x] = c;
    }
    __syncthreads();

    for (int bk = 0; bk < NBK; ++bk) {
        int c = cntL[bk];
        unsigned base = baseL[bk];
        for (int i = threadIdx.x; i < c; i += 512) {
            unsigned p = base + i;
            if (p < CAP) list[(size_t)(b * NBK + bk) * CAP + p] = stage[bk][i];
        }
    }
}

// Raycast over culled lists: block = (b, bucket); 1024 threads = 16 beams x 64
// seg-slices. seg[] gathered from global (128 KB, L2-resident; 4 distinct
// lines/wave/iter). 64-way LDS min-reduce, then outputs written inline.
__global__ __launch_bounds__(1024) void raycast9_kernel(
    const float4* __restrict__ seg, const float* __restrict__ pose,
    const unsigned* __restrict__ cnt, const unsigned short* __restrict__ list,
    float* __restrict__ out) {
    __shared__ float red[64][16];

    const int blk = blockIdx.x;          // 256 = 8b * 32bk
    const int b  = blk >> 5;
    const int bk = blk & (NBK - 1);
    const int t  = threadIdx.x;
    const int bm    = t & 15;
    const int slice = t >> 4;

    const float x1 = pose[b * 3 + 0];
    const float y1 = pose[b * 3 + 1];
    const float th = pose[b * 3 + 2];
    const int beam = (bk << 4) + bm;
    const float ang = (float)beam * ANG_STEP + th;
    const float rx = cosf(ang), ry = sinf(ang);
    const float INF = __builtin_inff();

    int n = (int)cnt[b * NBK + bk]; if (n > CAP) n = CAP;
    const unsigned short* __restrict__ lp = list + (size_t)(b * NBK + bk) * CAP;

    float umin = INF;
    for (int i = slice; i < n; i += 64) {
        int idx = lp[i];                 // broadcast within 16-lane group
        float4 v = seg[idx];
        float sx = v.z - v.x;
        float sy = v.w - v.y;
        float xd = x1 - v.x;
        float yd = y1 - v.y;
        float rxs = sy * rx - sx * ry;
        float na  = sx * yd - sy * xd;
        float nb  = rx * yd - ry * xd;
        float r   = __builtin_amdgcn_rcpf(rxs);
        float ua  = na * r;
        float ub  = nb * r;
        bool ok = (fabsf(rxs) >= EPS_PAR) & (ub >= 0.0f) & (ub <= 1.0f) & (ua >= 0.0f);
        umin = fminf(umin, ok ? ua : INF);
    }

    red[slice][bm] = umin;
    __syncthreads();
    if (slice < 16)
        red[slice][bm] = fminf(fminf(red[slice][bm], red[slice + 16][bm]),
                               fminf(red[slice + 32][bm], red[slice + 48][bm]));
    __syncthreads();

    if (t < 16) {
        float m = red[0][t];
        #pragma unroll
        for (int j = 1; j < 16; ++j) m = fminf(m, red[j][t]);

        const int gbeam = (bk << 4) + t;
        const float angf = (float)gbeam * ANG_STEP + th;
        const float rxf = cosf(angf), ryf = sinf(angf);

        if (isinf(m)) {
            // No valid intersection: ref takes u_a[0] (argmin of all-inf -> idx 0).
            float4 s0 = seg[0];
            float sx = s0.z - s0.x, sy = s0.w - s0.y;
            float xd = x1 - s0.x,   yd = y1 - s0.y;
            float rxs   = sy * rxf - sx * ryf;
            float num_a = sx * yd - sy * xd;
            m = (fabsf(rxs) < EPS_PAR) ? 0.0f : (num_a / rxs);
        }

        float ix = x1 + rxf * m;
        float iy = y1 + ryf * m;
        float dx = ix - x1, dy = iy - y1;
        float c = cosf(th), s = sinf(th);
        const int gb = b * L_OBS + gbeam;
        out[gb * 2 + 0] = ix;
        out[gb * 2 + 1] = iy;
        const int off = NB * L_OBS * 2;
        out[off + gb * 2 + 0] =  dx * c + dy * s;   // R = [[c,-s],[s,c]], out = d @ R
        out[off + gb * 2 + 1] = -dx * s + dy * c;
    }
}

// ---------------- fallback (R8, proven 21.2 us) if ws too small ----------------
#define SC2   32
#define CSEG2 (NSEG / SC2)
#define PART2_FLOATS (SC2 * NB * L_OBS)

__global__ __launch_bounds__(512) void raycast8_kernel(
    const float4* __restrict__ seg, const float* __restrict__ pose,
    float* __restrict__ part) {
    __shared__ float4 s4[CSEG2];
    __shared__ float  s_red[8][128];
    const int gid = blockIdx.x;
    const int sc = gid & (SC2 - 1);
    const int bg = (gid >> 5) & 3;
    const int b  = gid >> 7;
    const float x1 = pose[b * 3 + 0];
    const float y1 = pose[b * 3 + 1];
    const float th = pose[b * 3 + 2];
    const int t = threadIdx.x;
    if (t < CSEG2) {
        float4 v = seg[sc * CSEG2 + t];
        s4[t] = make_float4(v.z - v.x, v.w - v.y, x1 - v.x, y1 - v.y);
    }
    const int lane = t & 63;
    const int w    = t >> 6;
    const int beam0 = bg * 128 + lane;
    const float a0 = (float)beam0 * ANG_STEP + th;
    const float a1 = (float)(beam0 + 64) * ANG_STEP + th;
    const float rx0 = cosf(a0), ry0 = sinf(a0);
    const float rx1 = cosf(a1), ry1 = sinf(a1);
    const float INF = __builtin_inff();
    __syncthreads();
    float u0 = INF, u1 = INF;
    const float4* __restrict__ p = &s4[w * 32];
    #pragma unroll 8
    for (int i = 0; i < 32; ++i) {
        float4 s = p[i];
        float na = s.x * s.w - s.y * s.z;
        float rxs0 = s.y * rx0 - s.x * ry0;
        float nb0  = rx0 * s.w - ry0 * s.z;
        float r0   = __builtin_amdgcn_rcpf(rxs0);
        float ua0  = na  * r0;
        float ub0  = nb0 * r0;
        bool ok0 = (fabsf(rxs0) >= EPS_PAR) & (ub0 >= 0.0f) & (ub0 <= 1.0f) & (ua0 >= 0.0f);
        u0 = fminf(u0, ok0 ? ua0 : INF);
        float rxs1 = s.y * rx1 - s.x * ry1;
        float nb1  = rx1 * s.w - ry1 * s.z;
        float r1   = __builtin_amdgcn_rcpf(rxs1);
        float ua1  = na  * r1;
        float ub1  = nb1 * r1;
        bool ok1 = (fabsf(rxs1) >= EPS_PAR) & (ub1 >= 0.0f) & (ub1 <= 1.0f) & (ua1 >= 0.0f);
        u1 = fminf(u1, ok1 ? ua1 : INF);
    }
    s_red[w][lane]      = u0;
    s_red[w][lane + 64] = u1;
    __syncthreads();
    if (t < 128) {
        float m0 = fminf(fminf(s_red[0][t], s_red[1][t]),
                         fminf(s_red[2][t], s_red[3][t]));
        float m1 = fminf(fminf(s_red[4][t], s_red[5][t]),
                         fminf(s_red[6][t], s_red[7][t]));
        part[sc * (NB * L_OBS) + b * L_OBS + bg * 128 + t] = fminf(m0, m1);
    }
}

__global__ __launch_bounds__(256) void finalize7_kernel(
    const float4* __restrict__ seg, const float* __restrict__ pose,
    const float* __restrict__ part, float* __restrict__ out) {
    __shared__ float s_red[4][64];
    const int t    = threadIdx.x;
    const int lane = t & 63;
    const int q    = t >> 6;
    const int gbeam = blockIdx.x * 64 + lane;
    float u = INFINITY;
    #pragma unroll
    for (int j = 0; j < 8; ++j)
        u = fminf(u, part[(q * 8 + j) * (NB * L_OBS) + gbeam]);
    s_red[q][lane] = u;
    __syncthreads();
    if (t < 64) {
        const int gb   = blockIdx.x * 64 + t;
        const int b    = gb >> 9;
        const int beam = gb & (L_OBS - 1);
        const float x1 = pose[b * 3 + 0];
        const float y1 = pose[b * 3 + 1];
        const float th = pose[b * 3 + 2];
        const float ang = (float)beam * ANG_STEP + th;
        const float rx = cosf(ang), ry = sinf(ang);
        float m = fminf(fminf(s_red[0][t], s_red[1][t]),
                        fminf(s_red[2][t], s_red[3][t]));
        if (isinf(m)) {
            float4 s0 = seg[0];
            float sx = s0.z - s0.x, sy = s0.w - s0.y;
            float xd = x1 - s0.x,   yd = y1 - s0.y;
            float rxs   = sy * rx - sx * ry;
            float num_a = sx * yd - sy * xd;
            m = (fabsf(rxs) < EPS_PAR) ? 0.0f : (num_a / rxs);
        }
        float ix = x1 + rx * m;
        float iy = y1 + ry * m;
        float dx = ix - x1, dy = iy - y1;
        float c = cosf(th), s = sinf(th);
        out[gb * 2 + 0] = ix;
        out[gb * 2 + 1] = iy;
        const int off = NB * L_OBS * 2;
        out[off + gb * 2 + 0] =  dx * c + dy * s;
        out[off + gb * 2 + 1] = -dx * s + dy * c;
    }
}

extern "C" void kernel_launch(void* const* d_in, const int* in_sizes, int n_in,
                              void* d_out, int out_size, void* d_ws, size_t ws_size,
                              hipStream_t stream) {
    const float4* seg  = (const float4*)d_in[0];   // (N,4) float32
    const float*  pose = (const float*)d_in[1];    // (B,3) float32
    float* out = (float*)d_out;

    if (ws_size >= WS_NEED) {
        unsigned* cnt = (unsigned*)d_ws;
        unsigned short* list = (unsigned short*)((char*)d_ws + WS_CNT_BYTES);
        hipMemsetAsync(cnt, 0, WS_CNT_BYTES, stream);
        build_kernel<<<128, 512, 0, stream>>>(seg, pose, cnt, list);
        raycast9_kernel<<<NB * NBK, 1024, 0, stream>>>(seg, pose, cnt, list, out);
    } else {
        float* part = (float*)d_ws;
        raycast8_kernel<<<1024, 512, 0, stream>>>(seg, pose, part);
        finalize7_kernel<<<64, 256, 0, stream>>>(seg, pose, part, out);
    }
}

// Round 10
// 19.010 us; speedup vs baseline: 2.5798x; 2.5798x over previous
//
#include <hip/hip_runtime.h>
#include <math.h>

#define L_OBS   512
#define NSEG    8192
#define NB      8
#define EPS_PAR 1e-4f
#define ANG_STEP 0.012271846644580566f  // 2*pi / 512
#define INV_STEP 81.48733086305042f     // 1/ANG_STEP
#define PI_F     3.14159265358979f
#define TWOPI_F  6.28318530717959f
#define INV_2PI  0.15915494309189535f
#define MARG     2e-3f                  // rad margin >> atan2f error

// Block = (b, beamgroup of 128 beams, segchunk of 256 segs), 512 threads (8 waves).
// Stage-time wedge cull: a ray from P can hit segment AB (u_a>=0, u_b in [0,1])
// IFF its direction lies in the minor arc between dir(P->A) and dir(P->B)
// (width < pi). Block's beams span exactly pi/2, so ~half the segs are culled.
// Compacted into LDS (capacity == stage count -> no overflow possible; superset
// of hittable set -> exact min). Wave w strides compacted list by 8.
#define SC2   32
#define CSEG2 (NSEG / SC2)               // 256 segs per block
#define PART2_FLOATS (SC2 * NB * L_OBS)  // 512 KB

__global__ __launch_bounds__(512) void raycast10_kernel(
    const float4* __restrict__ seg, const float* __restrict__ pose,
    float* __restrict__ part) {
    __shared__ float4 s4[CSEG2];     // compacted {sx, sy, xd, yd}
    __shared__ float  s_red[8][128];
    __shared__ int    s_n;

    const int gid = blockIdx.x;      // 1024 = 8b * 4bg * 32sc
    const int sc = gid & (SC2 - 1);
    const int bg = (gid >> 5) & 3;
    const int b  = gid >> 7;

    const float x1 = pose[b * 3 + 0];
    const float y1 = pose[b * 3 + 1];
    const float th = pose[b * 3 + 2];

    const int t = threadIdx.x;
    if (t == 0) s_n = 0;
    __syncthreads();

    if (t < CSEG2) {
        float4 v = seg[sc * CSEG2 + t];
        float aA = atan2f(v.y - y1, v.x - x1);
        float aB = atan2f(v.w - y1, v.z - x1);
        float d  = aB - aA;
        if (d > PI_F) d -= TWOPI_F; else if (d < -PI_F) d += TWOPI_F;
        float lo  = (d >= 0.0f) ? aA : aB;
        float wdt = fabsf(d);

        bool keep;
        if (wdt > PI_F - 0.02f) {
            keep = true;                       // degenerate / pose near segment line
        } else {
            float a = lo - th;
            a -= floorf(a * INV_2PI) * TWOPI_F;          // [0, 2pi)
            int ilo = (int)floorf((a - MARG) * INV_STEP);          // >= -1
            int ihi = (int)floorf((a + wdt + MARG) * INV_STEP) + 1;
            if (ilo < 0) { ilo += 512; ihi += 512; }
            const int B0 = bg * 128, B1 = bg * 128 + 127;
            keep = (ilo <= B1 && ihi >= B0) || (ihi >= B0 + 512);
        }
        if (keep) {
            int pos = atomicAdd(&s_n, 1);
            s4[pos] = make_float4(v.z - v.x, v.w - v.y, x1 - v.x, y1 - v.y);
        }
    }

    const int lane = t & 63;
    const int w    = t >> 6;         // 0..7
    const int beam0 = bg * 128 + lane;
    const float a0 = (float)beam0 * ANG_STEP + th;
    const float a1 = (float)(beam0 + 64) * ANG_STEP + th;
    const float rx0 = cosf(a0), ry0 = sinf(a0);
    const float rx1 = cosf(a1), ry1 = sinf(a1);
    const float INF = __builtin_inff();
    __syncthreads();

    const int n = s_n;
    float u0 = INF, u1 = INF;
    #pragma unroll 4
    for (int i = w; i < n; i += 8) {
        float4 s = s4[i];                 // wave-uniform broadcast b128
        float na = s.x * s.w - s.y * s.z; // sx*yd - sy*xd

        float rxs0 = s.y * rx0 - s.x * ry0;
        float nb0  = rx0 * s.w - ry0 * s.z;
        float r0   = __builtin_amdgcn_rcpf(rxs0);
        float ua0  = na  * r0;
        float ub0  = nb0 * r0;
        bool ok0 = (fabsf(rxs0) >= EPS_PAR) & (ub0 >= 0.0f) & (ub0 <= 1.0f) & (ua0 >= 0.0f);
        u0 = fminf(u0, ok0 ? ua0 : INF);

        float rxs1 = s.y * rx1 - s.x * ry1;
        float nb1  = rx1 * s.w - ry1 * s.z;
        float r1   = __builtin_amdgcn_rcpf(rxs1);
        float ua1  = na  * r1;
        float ub1  = nb1 * r1;
        bool ok1 = (fabsf(rxs1) >= EPS_PAR) & (ub1 >= 0.0f) & (ub1 <= 1.0f) & (ua1 >= 0.0f);
        u1 = fminf(u1, ok1 ? ua1 : INF);
    }

    s_red[w][lane]      = u0;
    s_red[w][lane + 64] = u1;
    __syncthreads();
    if (t < 128) {
        float m0 = fminf(fminf(s_red[0][t], s_red[1][t]),
                         fminf(s_red[2][t], s_red[3][t]));
        float m1 = fminf(fminf(s_red[4][t], s_red[5][t]),
                         fminf(s_red[6][t], s_red[7][t]));
        part[sc * (NB * L_OBS) + b * L_OBS + bg * 128 + t] = fminf(m0, m1);
    }
}

// Parallel finalize (unchanged from R7/R8): 64 blocks x 256 threads.
__global__ __launch_bounds__(256) void finalize7_kernel(
    const float4* __restrict__ seg, const float* __restrict__ pose,
    const float* __restrict__ part, float* __restrict__ out) {
    __shared__ float s_red[4][64];

    const int t    = threadIdx.x;
    const int lane = t & 63;
    const int q    = t >> 6;
    const int gbeam = blockIdx.x * 64 + lane;   // 64 blocks cover 4096 beam-slots

    float u = INFINITY;
    #pragma unroll
    for (int j = 0; j < 8; ++j)
        u = fminf(u, part[(q * 8 + j) * (NB * L_OBS) + gbeam]);

    s_red[q][lane] = u;
    __syncthreads();
    if (t < 64) {
        const int gb   = blockIdx.x * 64 + t;
        const int b    = gb >> 9;
        const int beam = gb & (L_OBS - 1);
        const float x1 = pose[b * 3 + 0];
        const float y1 = pose[b * 3 + 1];
        const float th = pose[b * 3 + 2];
        const float ang = (float)beam * ANG_STEP + th;
        const float rx = cosf(ang), ry = sinf(ang);

        float m = fminf(fminf(s_red[0][t], s_red[1][t]),
                        fminf(s_red[2][t], s_red[3][t]));

        if (isinf(m)) {
            // No valid intersection: ref takes u_a[0] (argmin of all-inf -> idx 0).
            float4 s0 = seg[0];
            float sx = s0.z - s0.x, sy = s0.w - s0.y;
            float xd = x1 - s0.x,   yd = y1 - s0.y;
            float rxs   = sy * rx - sx * ry;
            float num_a = sx * yd - sy * xd;
            m = (fabsf(rxs) < EPS_PAR) ? 0.0f : (num_a / rxs);
        }

        float ix = x1 + rx * m;
        float iy = y1 + ry * m;
        float dx = ix - x1, dy = iy - y1;
        float c = cosf(th), s = sinf(th);
        out[gb * 2 + 0] = ix;
        out[gb * 2 + 1] = iy;
        const int off = NB * L_OBS * 2;
        out[off + gb * 2 + 0] =  dx * c + dy * s;   // R = [[c,-s],[s,c]], out = d @ R
        out[off + gb * 2 + 1] = -dx * s + dy * c;
    }
}

extern "C" void kernel_launch(void* const* d_in, const int* in_sizes, int n_in,
                              void* d_out, int out_size, void* d_ws, size_t ws_size,
                              hipStream_t stream) {
    const float4* seg  = (const float4*)d_in[0];   // (N,4) float32
    const float*  pose = (const float*)d_in[1];    // (B,3) float32
    float* out = (float*)d_out;
    float* part = (float*)d_ws;                    // [SC2][NB*L_OBS], 512 KB

    raycast10_kernel<<<1024, 512, 0, stream>>>(seg, pose, part);
    finalize7_kernel<<<64, 256, 0, stream>>>(seg, pose, part, out);
}